// Round 6
// baseline (307.309 us; speedup 1.0000x reference)
//
#include <hip/hip_runtime.h>

#define N_NODES 100000
#define PAD_N   100096                   // 782 * 128, padded M for GEMM tiles
#define IN_DIM 128
#define HID 128
#define N_REL 2
#define N_EDGES 500000
#define M_SEG (N_REL * N_NODES)          // 200000 (rel,node) segments
#define SCAN_BLK 1024
#define SCAN_NB ((M_SEG + SCAN_BLK - 1) / SCAN_BLK)   // 196

#define CVT_BLOCKS 12500                 // N_NODES*IN_DIM/4 / 256
#define PACK_BLOCKS 48                   // 2*12*8*64 / 256
#define HIST_BLOCKS 1954                 // ceil(N_EDGES/256)

typedef __attribute__((ext_vector_type(8))) short short8;
typedef __attribute__((ext_vector_type(4))) float float4v;

__device__ __forceinline__ unsigned short f2b(float f) {
    unsigned u = __float_as_uint(f);
    u += 0x7FFFu + ((u >> 16) & 1u);     // round-to-nearest-even
    return (unsigned short)(u >> 16);
}
__device__ __forceinline__ float blo(unsigned u) { return __uint_as_float(u << 16); }
__device__ __forceinline__ float bhi(unsigned u) { return __uint_as_float(u & 0xFFFF0000u); }

// ---------------------------------------------------------------------------
// Fused prep: cvt (x fp32->bf16) | pack (weights->B-frag order) | hist.
// ---------------------------------------------------------------------------
__global__ __launch_bounds__(256) void prep_kernel(
    const float* __restrict__ X, unsigned short* __restrict__ Xb,
    const float* __restrict__ Wroot1, const float* __restrict__ Wrel1,
    const float* __restrict__ Wroot2, const float* __restrict__ Wrel2,
    unsigned short* __restrict__ Wp,
    const int* __restrict__ ei, const int* __restrict__ et,
    unsigned* __restrict__ cnt)
{
    int bid = blockIdx.x;
    if (bid < CVT_BLOCKS) {
        int i = bid * 256 + threadIdx.x;
        if (i >= N_NODES * IN_DIM / 4) return;
        float4 v = ((const float4*)X)[i];
        ushort4 o;
        o.x = f2b(v.x); o.y = f2b(v.y); o.z = f2b(v.z); o.w = f2b(v.w);
        ((ushort4*)Xb)[i] = o;
    } else if (bid < CVT_BLOCKS + PACK_BLOCKS) {
        int tid = (bid - CVT_BLOCKS) * 256 + threadIdx.x;
        int layer = tid / 6144;
        int rem   = tid % 6144;
        int ks    = rem / 512;
        int rem2  = rem % 512;
        int nt    = rem2 / 64;
        int lane  = rem2 % 64;
        int seg = ks >> 2;
        int kl  = (ks & 3) * 32 + (lane >> 4) * 8;
        int chan = nt * 16 + (lane & 15);
        const float* Wroot = layer ? Wroot2 : Wroot1;
        const float* Wrel  = layer ? Wrel2  : Wrel1;
        const float* W = (seg == 0) ? Wroot : (Wrel + (size_t)(seg - 1) * 128 * 128);
        unsigned short* dst = Wp + (size_t)tid * 8;
        #pragma unroll
        for (int j = 0; j < 8; ++j)
            dst[j] = f2b(W[(size_t)(kl + j) * 128 + chan]);
    } else {
        int e = (bid - CVT_BLOCKS - PACK_BLOCKS) * 256 + threadIdx.x;
        if (e >= N_EDGES) return;
        int dst = ei[N_EDGES + e];
        int r = et[e];
        atomicAdd(cnt + (size_t)r * N_NODES + dst, 1u);
    }
}

// ---------------------------------------------------------------------------
// Scan chain for CSR row starts
// ---------------------------------------------------------------------------
__global__ __launch_bounds__(256) void scan1_kernel(
    const unsigned* __restrict__ cnt,
    unsigned* __restrict__ rs, unsigned* __restrict__ bsums)
{
    __shared__ unsigned sdata[256];
    int t = threadIdx.x;
    int base = blockIdx.x * SCAN_BLK + t * 4;
    unsigned v[4]; unsigned s = 0;
    #pragma unroll
    for (int j = 0; j < 4; ++j) {
        v[j] = (base + j < M_SEG) ? cnt[base + j] : 0u;
        s += v[j];
    }
    sdata[t] = s;
    __syncthreads();
    #pragma unroll
    for (int off = 1; off < 256; off <<= 1) {
        unsigned x = (t >= off) ? sdata[t - off] : 0u;
        __syncthreads();
        if (t >= off) sdata[t] += x;
        __syncthreads();
    }
    unsigned excl = (t > 0) ? sdata[t - 1] : 0u;
    if (t == 255) bsums[blockIdx.x] = sdata[255];
    unsigned run = excl;
    #pragma unroll
    for (int j = 0; j < 4; ++j) {
        if (base + j < M_SEG) rs[base + j] = run;
        run += v[j];
    }
}

__global__ __launch_bounds__(256) void scan2_kernel(unsigned* __restrict__ bsums)
{
    __shared__ unsigned sdata[256];
    int t = threadIdx.x;
    sdata[t] = (t < SCAN_NB) ? bsums[t] : 0u;
    __syncthreads();
    #pragma unroll
    for (int off = 1; off < 256; off <<= 1) {
        unsigned x = (t >= off) ? sdata[t - off] : 0u;
        __syncthreads();
        if (t >= off) sdata[t] += x;
        __syncthreads();
    }
    if (t < SCAN_NB) bsums[t] = (t > 0) ? sdata[t - 1] : 0u;
}

__global__ __launch_bounds__(256) void scan3_kernel(
    unsigned* __restrict__ rs, const unsigned* __restrict__ bsums,
    unsigned* __restrict__ cursor)
{
    int i = blockIdx.x * blockDim.x + threadIdx.x;
    if (i < M_SEG) {
        unsigned v = rs[i] + bsums[i >> 10];
        rs[i] = v;
        cursor[i] = v;
    }
    if (i == 0) rs[M_SEG] = N_EDGES;
}

__global__ __launch_bounds__(256) void fill_kernel(
    const int* __restrict__ ei, const int* __restrict__ et,
    unsigned* __restrict__ cursor, unsigned* __restrict__ csr)
{
    int e = blockIdx.x * blockDim.x + threadIdx.x;
    if (e >= N_EDGES) return;
    int src = ei[e];
    int dst = ei[N_EDGES + e];
    int r = et[e];
    unsigned pos = atomicAdd(cursor + (size_t)r * N_NODES + dst, 1u);
    csr[pos] = (unsigned)src;
}

// ---------------------------------------------------------------------------
// Gather-aggregate v3: 64 lanes per segment = 4 edge-slots x 16 ch-groups.
// Each trip covers 4 edges IN PARALLEL (no serial load chain for deg<=4,
// which is 87% of segments at avg degree 2.5).  Cross-edge reduction via
// shfl_xor(16/32); 16 lanes write the bf16 mean row (uint4 each).
// ---------------------------------------------------------------------------
__global__ __launch_bounds__(256) void gather_kernel(
    const unsigned short* __restrict__ Xb,   // [PAD_N][128] bf16
    const unsigned* __restrict__ rs,
    const unsigned* __restrict__ csr,
    unsigned short* __restrict__ agg)        // [2][PAD_N][128] bf16 means
{
    int t = blockIdx.x * blockDim.x + threadIdx.x;
    int seg = t >> 6;
    int lane = t & 63;
    if (seg >= M_SEG) return;
    const int e4  = lane >> 4;        // edge slot 0..3
    const int c16 = lane & 15;        // channel group (8 ch = uint4)

    unsigned start = rs[seg];
    unsigned end   = rs[seg + 1];

    float acc[8];
    #pragma unroll
    for (int j = 0; j < 8; ++j) acc[j] = 0.f;

    for (unsigned p = start; p < end; p += 4) {
        unsigned idx = p + e4;
        if (idx < end) {
            unsigned s = csr[idx];
            uint4 v = ((const uint4*)(Xb + (size_t)s * IN_DIM))[c16];
            acc[0] += blo(v.x); acc[1] += bhi(v.x);
            acc[2] += blo(v.y); acc[3] += bhi(v.y);
            acc[4] += blo(v.z); acc[5] += bhi(v.z);
            acc[6] += blo(v.w); acc[7] += bhi(v.w);
        }
    }

    // reduce across the 4 edge slots (lanes differing in bits 4,5)
    #pragma unroll
    for (int j = 0; j < 8; ++j) {
        acc[j] += __shfl_xor(acc[j], 16, 64);
        acc[j] += __shfl_xor(acc[j], 32, 64);
    }

    if (e4 == 0) {
        unsigned c = end - start;
        float scale = 1.0f / (float)(c > 0u ? c : 1u);
        int r = seg / N_NODES;
        int n = seg % N_NODES;
        uint4 o;
        o.x = ((unsigned)f2b(acc[1] * scale) << 16) | (unsigned)f2b(acc[0] * scale);
        o.y = ((unsigned)f2b(acc[3] * scale) << 16) | (unsigned)f2b(acc[2] * scale);
        o.z = ((unsigned)f2b(acc[5] * scale) << 16) | (unsigned)f2b(acc[4] * scale);
        o.w = ((unsigned)f2b(acc[7] * scale) << 16) | (unsigned)f2b(acc[6] * scale);
        ((uint4*)(agg + ((size_t)r * PAD_N + n) * HID))[c16] = o;
    }
}

// ---------------------------------------------------------------------------
// MFMA GEMM with double-buffered LDS B staging: 4 phases x 3 K-steps,
// two 24KB buffers.  stage(ph+1) issues before computing phase ph; the
// end-of-phase __syncthreads (vmcnt drain) is the readiness barrier.
// A-frags: depth-2 register prefetch.
// ---------------------------------------------------------------------------
template <bool FINAL>
__global__ __launch_bounds__(256) void gemm_kernel(
    const unsigned short* __restrict__ Xin,   // [PAD_N][128] bf16
    const unsigned short* __restrict__ agg,   // [2][PAD_N][128] bf16
    const unsigned short* __restrict__ Wp,    // packed [12][8][64][8] bf16
    const float* __restrict__ bias,           // [128] fp32
    unsigned short* __restrict__ Hout,        // [PAD_N][128] bf16 (!FINAL)
    const float* __restrict__ Wc,             // [128][2] fp32 (FINAL)
    const float* __restrict__ bc,             // [2] fp32 (FINAL)
    float* __restrict__ Out)                  // [N][2] fp32 (FINAL)
{
    __shared__ unsigned short ldsB[2][3 * 8 * 512];   // 2 x 24 KB

    const int t    = threadIdx.x;
    const int w    = t >> 6;          // wave 0..3
    const int lane = t & 63;
    const int l15  = lane & 15;
    const int quad = lane >> 4;
    const int rowbase = blockIdx.x * 128 + w * 32;   // this wave's 32 nodes
    const int koff = quad * 8;

    // stage the 24 frags of phase ph into buffer buf (6 per wave)
    auto stage = [&](int ph, int buf) {
        #pragma unroll
        for (int fi = 0; fi < 6; ++fi) {
            int f  = fi * 4 + w;          // 0..23
            int sl = f >> 3;              // phase-local K-step 0..2
            int nt = f & 7;
            int ks = ph * 3 + sl;
            const unsigned short* g = Wp + ((size_t)(ks * 8 + nt) * 64 + lane) * 8;
            unsigned short* l = &ldsB[buf][(size_t)(sl * 8 + nt) * 512];  // wave-uniform
            __builtin_amdgcn_global_load_lds(
                (const __attribute__((address_space(1))) unsigned int*)g,
                (__attribute__((address_space(3))) unsigned int*)l, 16, 0, 0);
        }
    };

    // A-frag base pointers (constant over ks)
    const unsigned short* aS0m0 = Xin + (size_t)(rowbase + l15) * 128 + koff;
    const unsigned short* aS0m1 = aS0m0 + 16 * 128;
    const unsigned short* aS1m0 = agg + (size_t)(rowbase + l15) * 128 + koff;
    const unsigned short* aS1m1 = aS1m0 + 16 * 128;
    const unsigned short* aS2m0 = aS1m0 + (size_t)PAD_N * 128;
    const unsigned short* aS2m1 = aS2m0 + 16 * 128;

    auto aload = [&](int ks, int mt) -> short8 {
        int seg = ks >> 2;
        int kc  = (ks & 3) * 32;
        const unsigned short* p =
            (seg == 0) ? (mt ? aS0m1 : aS0m0) :
            (seg == 1) ? (mt ? aS1m1 : aS1m0) :
                         (mt ? aS2m1 : aS2m0);
        return *(const short8*)(p + kc);
    };

    float4v acc[2][8];
    #pragma unroll
    for (int nt = 0; nt < 8; ++nt) {
        float bv = bias[nt * 16 + l15];
        #pragma unroll
        for (int mt = 0; mt < 2; ++mt)
            acc[mt][nt] = float4v{bv, bv, bv, bv};
    }

    short8 a0[12], a1[12];
    stage(0, 0);
    a0[0] = aload(0, 0); a1[0] = aload(0, 1);
    a0[1] = aload(1, 0); a1[1] = aload(1, 1);
    __syncthreads();                      // phase-0 B staged (vmcnt drained)

    #pragma unroll
    for (int ph = 0; ph < 4; ++ph) {
        if (ph < 3) stage(ph + 1, (ph + 1) & 1);   // overlap staging with compute
        #pragma unroll
        for (int sl = 0; sl < 3; ++sl) {
            int ks = ph * 3 + sl;
            if (ks + 2 < 12) { a0[ks + 2] = aload(ks + 2, 0); a1[ks + 2] = aload(ks + 2, 1); }
            short8 b[8];
            #pragma unroll
            for (int nt = 0; nt < 8; ++nt)
                b[nt] = *(const short8*)(&ldsB[ph & 1][(size_t)(sl * 8 + nt) * 512] + lane * 8);
            #pragma unroll
            for (int nt = 0; nt < 8; ++nt) {
                acc[0][nt] = __builtin_amdgcn_mfma_f32_16x16x32_bf16(a0[ks], b[nt], acc[0][nt], 0, 0, 0);
                acc[1][nt] = __builtin_amdgcn_mfma_f32_16x16x32_bf16(a1[ks], b[nt], acc[1][nt], 0, 0, 0);
            }
        }
        __syncthreads();   // readers done with buf(ph&1); stage(ph+1) drained
    }

    if (!FINAL) {
        // D layout: row = quad*4 + r, col = l15 (within each 16x16 tile)
        #pragma unroll
        for (int mt = 0; mt < 2; ++mt) {
            #pragma unroll
            for (int r = 0; r < 4; ++r) {
                int node = rowbase + mt * 16 + quad * 4 + r;
                unsigned short* hp = Hout + (size_t)node * 128 + l15;
                #pragma unroll
                for (int nt = 0; nt < 8; ++nt)
                    hp[nt * 16] = f2b(fmaxf(acc[mt][nt][r], 0.f));
            }
        }
    } else {
        float wc0[8], wc1[8];
        #pragma unroll
        for (int nt = 0; nt < 8; ++nt) {
            wc0[nt] = Wc[(nt * 16 + l15) * 2 + 0];
            wc1[nt] = Wc[(nt * 16 + l15) * 2 + 1];
        }
        float b0 = bc[0], b1 = bc[1];
        #pragma unroll
        for (int mt = 0; mt < 2; ++mt) {
            #pragma unroll
            for (int r = 0; r < 4; ++r) {
                float l0 = 0.f, l1 = 0.f;
                #pragma unroll
                for (int nt = 0; nt < 8; ++nt) {
                    float h = fmaxf(acc[mt][nt][r], 0.f);
                    l0 += h * wc0[nt];
                    l1 += h * wc1[nt];
                }
                #pragma unroll
                for (int off = 8; off > 0; off >>= 1) {
                    l0 += __shfl_down(l0, off, 16);
                    l1 += __shfl_down(l1, off, 16);
                }
                int node = rowbase + mt * 16 + quad * 4 + r;
                if (l15 == 0 && node < N_NODES) {
                    Out[(size_t)node * 2 + 0] = l0 + b0;
                    Out[(size_t)node * 2 + 1] = l1 + b1;
                }
            }
        }
    }
}

extern "C" void kernel_launch(void* const* d_in, const int* in_sizes, int n_in,
                              void* d_out, int out_size, void* d_ws, size_t ws_size,
                              hipStream_t stream)
{
    const float* x      = (const float*)d_in[0];
    const int*   ei     = (const int*)d_in[1];
    const int*   et     = (const int*)d_in[2];
    const float* Wrel1  = (const float*)d_in[3];
    const float* Wroot1 = (const float*)d_in[4];
    const float* b1     = (const float*)d_in[5];
    const float* Wrel2  = (const float*)d_in[6];
    const float* Wroot2 = (const float*)d_in[7];
    const float* b2     = (const float*)d_in[8];
    const float* Wc     = (const float*)d_in[9];
    const float* bc     = (const float*)d_in[10];
    float* out = (float*)d_out;

    char* ws = (char*)d_ws;
    size_t off = 0;
    auto alloc = [&](size_t bytes) {
        void* p = ws + off;
        off += (bytes + 255) & ~(size_t)255;
        return p;
    };
    unsigned short* aggb  = (unsigned short*)alloc((size_t)N_REL * PAD_N * HID * 2);
    unsigned short* xb    = (unsigned short*)alloc((size_t)PAD_N * IN_DIM * 2);
    unsigned short* h1b   = (unsigned short*)alloc((size_t)PAD_N * HID * 2);
    unsigned short* Wp    = (unsigned short*)alloc((size_t)2 * 12 * 8 * 64 * 8 * 2);
    unsigned*       rs    = (unsigned*)alloc((size_t)(M_SEG + 1) * 4);
    unsigned*       cursor= (unsigned*)alloc((size_t)M_SEG * 4);
    unsigned*       bsums = (unsigned*)alloc(256 * 4);
    unsigned*       csr   = (unsigned*)alloc((size_t)N_EDGES * 4);

    const int edge_blocks   = (N_EDGES + 255) / 256;
    const int seg_blocks    = (M_SEG + 255) / 256;
    const int gather_blocks = (M_SEG * 64 + 255) / 256;   // 50000
    const int gemm_blocks   = PAD_N / 128;                // 782
    const int prep_blocks   = CVT_BLOCKS + PACK_BLOCKS + HIST_BLOCKS;

    // ---- CSR build + conversions (graph identical for both layers) ----
    hipMemsetAsync(cursor, 0, (size_t)M_SEG * 4, stream);
    prep_kernel<<<prep_blocks, 256, 0, stream>>>(
        x, xb, Wroot1, Wrel1, Wroot2, Wrel2, Wp, ei, et, cursor);
    scan1_kernel<<<SCAN_NB, 256, 0, stream>>>(cursor, rs, bsums);
    scan2_kernel<<<1, 256, 0, stream>>>(bsums);
    scan3_kernel<<<seg_blocks, 256, 0, stream>>>(rs, bsums, cursor);
    fill_kernel<<<edge_blocks, 256, 0, stream>>>(ei, et, cursor, csr);

    // ---- layer 1 ----
    gather_kernel<<<gather_blocks, 256, 0, stream>>>(xb, rs, csr, aggb);
    gemm_kernel<false><<<gemm_blocks, 256, 0, stream>>>(
        xb, aggb, Wp, b1, h1b, nullptr, nullptr, nullptr);

    // ---- layer 2 ----
    gather_kernel<<<gather_blocks, 256, 0, stream>>>(h1b, rs, csr, aggb);
    gemm_kernel<true><<<gemm_blocks, 256, 0, stream>>>(
        h1b, aggb, Wp + (size_t)12 * 8 * 64 * 8, b2, nullptr, Wc, bc, out);
}

// Round 7
// 277.442 us; speedup vs baseline: 1.1077x; 1.1077x over previous
//
#include <hip/hip_runtime.h>

#define N_NODES 100000
#define PAD_N   100096                   // 782 * 128, padded M for GEMM tiles
#define IN_DIM 128
#define HID 128
#define N_REL 2
#define N_EDGES 500000
#define M_SEG (N_REL * N_NODES)          // 200000 (rel,node) segments
#define SCAN_BLK 1024
#define SCAN_NB ((M_SEG + SCAN_BLK - 1) / SCAN_BLK)   // 196

#define CVT_BLOCKS 12500                 // N_NODES*IN_DIM/4 / 256
#define PACK_BLOCKS 48                   // 2*12*8*64 / 256
#define HIST_BLOCKS 1954                 // ceil(N_EDGES/256)

typedef __attribute__((ext_vector_type(8))) short short8;
typedef __attribute__((ext_vector_type(4))) float float4v;

__device__ __forceinline__ unsigned short f2b(float f) {
    unsigned u = __float_as_uint(f);
    u += 0x7FFFu + ((u >> 16) & 1u);     // round-to-nearest-even
    return (unsigned short)(u >> 16);
}
__device__ __forceinline__ float blo(unsigned u) { return __uint_as_float(u << 16); }
__device__ __forceinline__ float bhi(unsigned u) { return __uint_as_float(u & 0xFFFF0000u); }

// ---------------------------------------------------------------------------
// Fused prep: cvt (x fp32->bf16) | pack (weights->B-frag order) | hist.
// ---------------------------------------------------------------------------
__global__ __launch_bounds__(256) void prep_kernel(
    const float* __restrict__ X, unsigned short* __restrict__ Xb,
    const float* __restrict__ Wroot1, const float* __restrict__ Wrel1,
    const float* __restrict__ Wroot2, const float* __restrict__ Wrel2,
    unsigned short* __restrict__ Wp,
    const int* __restrict__ ei, const int* __restrict__ et,
    unsigned* __restrict__ cnt)
{
    int bid = blockIdx.x;
    if (bid < CVT_BLOCKS) {
        int i = bid * 256 + threadIdx.x;
        if (i >= N_NODES * IN_DIM / 4) return;
        float4 v = ((const float4*)X)[i];
        ushort4 o;
        o.x = f2b(v.x); o.y = f2b(v.y); o.z = f2b(v.z); o.w = f2b(v.w);
        ((ushort4*)Xb)[i] = o;
    } else if (bid < CVT_BLOCKS + PACK_BLOCKS) {
        int tid = (bid - CVT_BLOCKS) * 256 + threadIdx.x;
        int layer = tid / 6144;
        int rem   = tid % 6144;
        int ks    = rem / 512;
        int rem2  = rem % 512;
        int nt    = rem2 / 64;
        int lane  = rem2 % 64;
        int seg = ks >> 2;
        int kl  = (ks & 3) * 32 + (lane >> 4) * 8;
        int chan = nt * 16 + (lane & 15);
        const float* Wroot = layer ? Wroot2 : Wroot1;
        const float* Wrel  = layer ? Wrel2  : Wrel1;
        const float* W = (seg == 0) ? Wroot : (Wrel + (size_t)(seg - 1) * 128 * 128);
        unsigned short* dst = Wp + (size_t)tid * 8;
        #pragma unroll
        for (int j = 0; j < 8; ++j)
            dst[j] = f2b(W[(size_t)(kl + j) * 128 + chan]);
    } else {
        int e = (bid - CVT_BLOCKS - PACK_BLOCKS) * 256 + threadIdx.x;
        if (e >= N_EDGES) return;
        int dst = ei[N_EDGES + e];
        int r = et[e];
        atomicAdd(cnt + (size_t)r * N_NODES + dst, 1u);
    }
}

// ---------------------------------------------------------------------------
// Scan chain for CSR row starts
// ---------------------------------------------------------------------------
__global__ __launch_bounds__(256) void scan1_kernel(
    const unsigned* __restrict__ cnt,
    unsigned* __restrict__ rs, unsigned* __restrict__ bsums)
{
    __shared__ unsigned sdata[256];
    int t = threadIdx.x;
    int base = blockIdx.x * SCAN_BLK + t * 4;
    unsigned v[4]; unsigned s = 0;
    #pragma unroll
    for (int j = 0; j < 4; ++j) {
        v[j] = (base + j < M_SEG) ? cnt[base + j] : 0u;
        s += v[j];
    }
    sdata[t] = s;
    __syncthreads();
    #pragma unroll
    for (int off = 1; off < 256; off <<= 1) {
        unsigned x = (t >= off) ? sdata[t - off] : 0u;
        __syncthreads();
        if (t >= off) sdata[t] += x;
        __syncthreads();
    }
    unsigned excl = (t > 0) ? sdata[t - 1] : 0u;
    if (t == 255) bsums[blockIdx.x] = sdata[255];
    unsigned run = excl;
    #pragma unroll
    for (int j = 0; j < 4; ++j) {
        if (base + j < M_SEG) rs[base + j] = run;
        run += v[j];
    }
}

__global__ __launch_bounds__(256) void scan2_kernel(unsigned* __restrict__ bsums)
{
    __shared__ unsigned sdata[256];
    int t = threadIdx.x;
    sdata[t] = (t < SCAN_NB) ? bsums[t] : 0u;
    __syncthreads();
    #pragma unroll
    for (int off = 1; off < 256; off <<= 1) {
        unsigned x = (t >= off) ? sdata[t - off] : 0u;
        __syncthreads();
        if (t >= off) sdata[t] += x;
        __syncthreads();
    }
    if (t < SCAN_NB) bsums[t] = (t > 0) ? sdata[t - 1] : 0u;
}

__global__ __launch_bounds__(256) void scan3_kernel(
    unsigned* __restrict__ rs, const unsigned* __restrict__ bsums,
    unsigned* __restrict__ cursor)
{
    int i = blockIdx.x * blockDim.x + threadIdx.x;
    if (i < M_SEG) {
        unsigned v = rs[i] + bsums[i >> 10];
        rs[i] = v;
        cursor[i] = v;
    }
    if (i == 0) rs[M_SEG] = N_EDGES;
}

__global__ __launch_bounds__(256) void fill_kernel(
    const int* __restrict__ ei, const int* __restrict__ et,
    unsigned* __restrict__ cursor, unsigned* __restrict__ csr)
{
    int e = blockIdx.x * blockDim.x + threadIdx.x;
    if (e >= N_EDGES) return;
    int src = ei[e];
    int dst = ei[N_EDGES + e];
    int r = et[e];
    unsigned pos = atomicAdd(cursor + (size_t)r * N_NODES + dst, 1u);
    csr[pos] = (unsigned)src;
}

// ---------------------------------------------------------------------------
// Gather-aggregate v4: 32 lanes per segment = 2 edge-slots x 16 ch-groups
// (uint4 = 8 channels per lane).  2 segments per wave (v2's wave economy),
// ~1.7 serial trips avg (vs 2.5), one shfl_xor(16) reduction at the end.
// 32-bit indexed row loads off the SGPR base (no per-edge 64-bit addr math).
// ---------------------------------------------------------------------------
__global__ __launch_bounds__(256) void gather_kernel(
    const unsigned short* __restrict__ Xb,   // [PAD_N][128] bf16
    const unsigned* __restrict__ rs,
    const unsigned* __restrict__ csr,
    unsigned short* __restrict__ agg)        // [2][PAD_N][128] bf16 means
{
    int t = blockIdx.x * blockDim.x + threadIdx.x;
    int seg = t >> 5;                 // 32 lanes per segment
    int lane = t & 31;
    if (seg >= M_SEG) return;
    const int e2  = lane >> 4;        // edge slot 0..1
    const int c16 = lane & 15;        // channel group (8 ch = uint4)

    unsigned start = rs[seg];
    unsigned end   = rs[seg + 1];

    const uint4* __restrict__ X4 = (const uint4*)Xb;   // 16B units

    float acc[8];
    #pragma unroll
    for (int j = 0; j < 8; ++j) acc[j] = 0.f;

    for (unsigned p = start + e2; p < end; p += 2) {
        unsigned s = csr[p];
        uint4 v = X4[(s << 4) | (unsigned)c16];        // 32-bit index, SGPR base
        acc[0] += blo(v.x); acc[1] += bhi(v.x);
        acc[2] += blo(v.y); acc[3] += bhi(v.y);
        acc[4] += blo(v.z); acc[5] += bhi(v.z);
        acc[6] += blo(v.w); acc[7] += bhi(v.w);
    }

    // reduce across the 2 edge slots (lane bit 4)
    #pragma unroll
    for (int j = 0; j < 8; ++j)
        acc[j] += __shfl_xor(acc[j], 16, 32);

    if (e2 == 0) {
        unsigned c = end - start;
        float scale = 1.0f / (float)(c > 0u ? c : 1u);
        int r = seg / N_NODES;
        int n = seg % N_NODES;
        uint4 o;
        o.x = ((unsigned)f2b(acc[1] * scale) << 16) | (unsigned)f2b(acc[0] * scale);
        o.y = ((unsigned)f2b(acc[3] * scale) << 16) | (unsigned)f2b(acc[2] * scale);
        o.z = ((unsigned)f2b(acc[5] * scale) << 16) | (unsigned)f2b(acc[4] * scale);
        o.w = ((unsigned)f2b(acc[7] * scale) << 16) | (unsigned)f2b(acc[6] * scale);
        ((uint4*)(agg + ((size_t)r * PAD_N + n) * HID))[c16] = o;
    }
}

// ---------------------------------------------------------------------------
// MFMA GEMM with double-buffered LDS B staging: 4 phases x 3 K-steps,
// two 24KB buffers.  stage(ph+1) issues before computing phase ph; the
// end-of-phase __syncthreads (vmcnt drain) is the readiness barrier.
// A-frags: depth-2 register prefetch.
// ---------------------------------------------------------------------------
template <bool FINAL>
__global__ __launch_bounds__(256) void gemm_kernel(
    const unsigned short* __restrict__ Xin,   // [PAD_N][128] bf16
    const unsigned short* __restrict__ agg,   // [2][PAD_N][128] bf16
    const unsigned short* __restrict__ Wp,    // packed [12][8][64][8] bf16
    const float* __restrict__ bias,           // [128] fp32
    unsigned short* __restrict__ Hout,        // [PAD_N][128] bf16 (!FINAL)
    const float* __restrict__ Wc,             // [128][2] fp32 (FINAL)
    const float* __restrict__ bc,             // [2] fp32 (FINAL)
    float* __restrict__ Out)                  // [N][2] fp32 (FINAL)
{
    __shared__ unsigned short ldsB[2][3 * 8 * 512];   // 2 x 24 KB

    const int t    = threadIdx.x;
    const int w    = t >> 6;          // wave 0..3
    const int lane = t & 63;
    const int l15  = lane & 15;
    const int quad = lane >> 4;
    const int rowbase = blockIdx.x * 128 + w * 32;   // this wave's 32 nodes
    const int koff = quad * 8;

    // stage the 24 frags of phase ph into buffer buf (6 per wave)
    auto stage = [&](int ph, int buf) {
        #pragma unroll
        for (int fi = 0; fi < 6; ++fi) {
            int f  = fi * 4 + w;          // 0..23
            int sl = f >> 3;              // phase-local K-step 0..2
            int nt = f & 7;
            int ks = ph * 3 + sl;
            const unsigned short* g = Wp + ((size_t)(ks * 8 + nt) * 64 + lane) * 8;
            unsigned short* l = &ldsB[buf][(size_t)(sl * 8 + nt) * 512];  // wave-uniform
            __builtin_amdgcn_global_load_lds(
                (const __attribute__((address_space(1))) unsigned int*)g,
                (__attribute__((address_space(3))) unsigned int*)l, 16, 0, 0);
        }
    };

    // A-frag base pointers (constant over ks)
    const unsigned short* aS0m0 = Xin + (size_t)(rowbase + l15) * 128 + koff;
    const unsigned short* aS0m1 = aS0m0 + 16 * 128;
    const unsigned short* aS1m0 = agg + (size_t)(rowbase + l15) * 128 + koff;
    const unsigned short* aS1m1 = aS1m0 + 16 * 128;
    const unsigned short* aS2m0 = aS1m0 + (size_t)PAD_N * 128;
    const unsigned short* aS2m1 = aS2m0 + 16 * 128;

    auto aload = [&](int ks, int mt) -> short8 {
        int seg = ks >> 2;
        int kc  = (ks & 3) * 32;
        const unsigned short* p =
            (seg == 0) ? (mt ? aS0m1 : aS0m0) :
            (seg == 1) ? (mt ? aS1m1 : aS1m0) :
                         (mt ? aS2m1 : aS2m0);
        return *(const short8*)(p + kc);
    };

    float4v acc[2][8];
    #pragma unroll
    for (int nt = 0; nt < 8; ++nt) {
        float bv = bias[nt * 16 + l15];
        #pragma unroll
        for (int mt = 0; mt < 2; ++mt)
            acc[mt][nt] = float4v{bv, bv, bv, bv};
    }

    short8 a0[12], a1[12];
    stage(0, 0);
    a0[0] = aload(0, 0); a1[0] = aload(0, 1);
    a0[1] = aload(1, 0); a1[1] = aload(1, 1);
    __syncthreads();                      // phase-0 B staged (vmcnt drained)

    #pragma unroll
    for (int ph = 0; ph < 4; ++ph) {
        if (ph < 3) stage(ph + 1, (ph + 1) & 1);   // overlap staging with compute
        #pragma unroll
        for (int sl = 0; sl < 3; ++sl) {
            int ks = ph * 3 + sl;
            if (ks + 2 < 12) { a0[ks + 2] = aload(ks + 2, 0); a1[ks + 2] = aload(ks + 2, 1); }
            short8 b[8];
            #pragma unroll
            for (int nt = 0; nt < 8; ++nt)
                b[nt] = *(const short8*)(&ldsB[ph & 1][(size_t)(sl * 8 + nt) * 512] + lane * 8);
            #pragma unroll
            for (int nt = 0; nt < 8; ++nt) {
                acc[0][nt] = __builtin_amdgcn_mfma_f32_16x16x32_bf16(a0[ks], b[nt], acc[0][nt], 0, 0, 0);
                acc[1][nt] = __builtin_amdgcn_mfma_f32_16x16x32_bf16(a1[ks], b[nt], acc[1][nt], 0, 0, 0);
            }
        }
        __syncthreads();   // readers done with buf(ph&1); stage(ph+1) drained
    }

    if (!FINAL) {
        // D layout: row = quad*4 + r, col = l15 (within each 16x16 tile)
        #pragma unroll
        for (int mt = 0; mt < 2; ++mt) {
            #pragma unroll
            for (int r = 0; r < 4; ++r) {
                int node = rowbase + mt * 16 + quad * 4 + r;
                unsigned short* hp = Hout + (size_t)node * 128 + l15;
                #pragma unroll
                for (int nt = 0; nt < 8; ++nt)
                    hp[nt * 16] = f2b(fmaxf(acc[mt][nt][r], 0.f));
            }
        }
    } else {
        float wc0[8], wc1[8];
        #pragma unroll
        for (int nt = 0; nt < 8; ++nt) {
            wc0[nt] = Wc[(nt * 16 + l15) * 2 + 0];
            wc1[nt] = Wc[(nt * 16 + l15) * 2 + 1];
        }
        float b0 = bc[0], b1 = bc[1];
        #pragma unroll
        for (int mt = 0; mt < 2; ++mt) {
            #pragma unroll
            for (int r = 0; r < 4; ++r) {
                float l0 = 0.f, l1 = 0.f;
                #pragma unroll
                for (int nt = 0; nt < 8; ++nt) {
                    float h = fmaxf(acc[mt][nt][r], 0.f);
                    l0 += h * wc0[nt];
                    l1 += h * wc1[nt];
                }
                #pragma unroll
                for (int off = 8; off > 0; off >>= 1) {
                    l0 += __shfl_down(l0, off, 16);
                    l1 += __shfl_down(l1, off, 16);
                }
                int node = rowbase + mt * 16 + quad * 4 + r;
                if (l15 == 0 && node < N_NODES) {
                    Out[(size_t)node * 2 + 0] = l0 + b0;
                    Out[(size_t)node * 2 + 1] = l1 + b1;
                }
            }
        }
    }
}

extern "C" void kernel_launch(void* const* d_in, const int* in_sizes, int n_in,
                              void* d_out, int out_size, void* d_ws, size_t ws_size,
                              hipStream_t stream)
{
    const float* x      = (const float*)d_in[0];
    const int*   ei     = (const int*)d_in[1];
    const int*   et     = (const int*)d_in[2];
    const float* Wrel1  = (const float*)d_in[3];
    const float* Wroot1 = (const float*)d_in[4];
    const float* b1     = (const float*)d_in[5];
    const float* Wrel2  = (const float*)d_in[6];
    const float* Wroot2 = (const float*)d_in[7];
    const float* b2     = (const float*)d_in[8];
    const float* Wc     = (const float*)d_in[9];
    const float* bc     = (const float*)d_in[10];
    float* out = (float*)d_out;

    char* ws = (char*)d_ws;
    size_t off = 0;
    auto alloc = [&](size_t bytes) {
        void* p = ws + off;
        off += (bytes + 255) & ~(size_t)255;
        return p;
    };
    unsigned short* aggb  = (unsigned short*)alloc((size_t)N_REL * PAD_N * HID * 2);
    unsigned short* xb    = (unsigned short*)alloc((size_t)PAD_N * IN_DIM * 2);
    unsigned short* h1b   = (unsigned short*)alloc((size_t)PAD_N * HID * 2);
    unsigned short* Wp    = (unsigned short*)alloc((size_t)2 * 12 * 8 * 64 * 8 * 2);
    unsigned*       rs    = (unsigned*)alloc((size_t)(M_SEG + 1) * 4);
    unsigned*       cursor= (unsigned*)alloc((size_t)M_SEG * 4);
    unsigned*       bsums = (unsigned*)alloc(256 * 4);
    unsigned*       csr   = (unsigned*)alloc((size_t)N_EDGES * 4);

    const int edge_blocks   = (N_EDGES + 255) / 256;
    const int seg_blocks    = (M_SEG + 255) / 256;
    const int gather_blocks = (M_SEG * 32 + 255) / 256;   // 25000
    const int gemm_blocks   = PAD_N / 128;                // 782
    const int prep_blocks   = CVT_BLOCKS + PACK_BLOCKS + HIST_BLOCKS;

    // ---- CSR build + conversions (graph identical for both layers) ----
    hipMemsetAsync(cursor, 0, (size_t)M_SEG * 4, stream);
    prep_kernel<<<prep_blocks, 256, 0, stream>>>(
        x, xb, Wroot1, Wrel1, Wroot2, Wrel2, Wp, ei, et, cursor);
    scan1_kernel<<<SCAN_NB, 256, 0, stream>>>(cursor, rs, bsums);
    scan2_kernel<<<1, 256, 0, stream>>>(bsums);
    scan3_kernel<<<seg_blocks, 256, 0, stream>>>(rs, bsums, cursor);
    fill_kernel<<<edge_blocks, 256, 0, stream>>>(ei, et, cursor, csr);

    // ---- layer 1 ----
    gather_kernel<<<gather_blocks, 256, 0, stream>>>(xb, rs, csr, aggb);
    gemm_kernel<false><<<gemm_blocks, 256, 0, stream>>>(
        xb, aggb, Wp, b1, h1b, nullptr, nullptr, nullptr);

    // ---- layer 2 ----
    gather_kernel<<<gather_blocks, 256, 0, stream>>>(h1b, rs, csr, aggb);
    gemm_kernel<true><<<gemm_blocks, 256, 0, stream>>>(
        h1b, aggb, Wp + (size_t)12 * 8 * 64 * 8, b2, nullptr, Wc, bc, out);
}

// Round 8
// 270.062 us; speedup vs baseline: 1.1379x; 1.0273x over previous
//
#include <hip/hip_runtime.h>
#include <hip/hip_fp16.h>

#define N_NODES 100000
#define PAD_N   100096                   // 782 * 128, padded M for GEMM tiles
#define IN_DIM 128
#define HID 128
#define N_REL 2
#define N_EDGES 500000
#define M_SEG (N_REL * N_NODES)          // 200000 (rel,node) segments
#define SCAN_BLK 1024
#define SCAN_NB ((M_SEG + SCAN_BLK - 1) / SCAN_BLK)   // 196

#define CVT_BLOCKS 12500                 // N_NODES*IN_DIM/4 / 256
#define PACK_BLOCKS 48                   // 2*12*8*64 / 256
#define HIST_BLOCKS 1954                 // ceil(N_EDGES/256)

typedef __attribute__((ext_vector_type(8))) _Float16 half8;
typedef __attribute__((ext_vector_type(4))) float float4v;

__device__ __forceinline__ unsigned short f2h(float f) {
    return __half_as_ushort(__float2half(f));   // RNE
}

// ---------------------------------------------------------------------------
// Fused prep: cvt (x fp32->fp16) | pack (weights->B-frag order, fp16) | hist.
// ---------------------------------------------------------------------------
__global__ __launch_bounds__(256) void prep_kernel(
    const float* __restrict__ X, unsigned short* __restrict__ Xb,
    const float* __restrict__ Wroot1, const float* __restrict__ Wrel1,
    const float* __restrict__ Wroot2, const float* __restrict__ Wrel2,
    unsigned short* __restrict__ Wp,
    const int* __restrict__ ei, const int* __restrict__ et,
    unsigned* __restrict__ cnt)
{
    int bid = blockIdx.x;
    if (bid < CVT_BLOCKS) {
        int i = bid * 256 + threadIdx.x;
        if (i >= N_NODES * IN_DIM / 4) return;
        float4 v = ((const float4*)X)[i];
        ushort4 o;
        o.x = f2h(v.x); o.y = f2h(v.y); o.z = f2h(v.z); o.w = f2h(v.w);
        ((ushort4*)Xb)[i] = o;
    } else if (bid < CVT_BLOCKS + PACK_BLOCKS) {
        int tid = (bid - CVT_BLOCKS) * 256 + threadIdx.x;
        int layer = tid / 6144;
        int rem   = tid % 6144;
        int ks    = rem / 512;
        int rem2  = rem % 512;
        int nt    = rem2 / 64;
        int lane  = rem2 % 64;
        int seg = ks >> 2;
        int kl  = (ks & 3) * 32 + (lane >> 4) * 8;
        int chan = nt * 16 + (lane & 15);
        const float* Wroot = layer ? Wroot2 : Wroot1;
        const float* Wrel  = layer ? Wrel2  : Wrel1;
        const float* W = (seg == 0) ? Wroot : (Wrel + (size_t)(seg - 1) * 128 * 128);
        unsigned short* dst = Wp + (size_t)tid * 8;
        #pragma unroll
        for (int j = 0; j < 8; ++j)
            dst[j] = f2h(W[(size_t)(kl + j) * 128 + chan]);
    } else {
        int e = (bid - CVT_BLOCKS - PACK_BLOCKS) * 256 + threadIdx.x;
        if (e >= N_EDGES) return;
        int dst = ei[N_EDGES + e];
        int r = et[e];
        atomicAdd(cnt + (size_t)r * N_NODES + dst, 1u);
    }
}

// ---------------------------------------------------------------------------
// Scan chain for CSR row starts
// ---------------------------------------------------------------------------
__global__ __launch_bounds__(256) void scan1_kernel(
    const unsigned* __restrict__ cnt,
    unsigned* __restrict__ rs, unsigned* __restrict__ bsums)
{
    __shared__ unsigned sdata[256];
    int t = threadIdx.x;
    int base = blockIdx.x * SCAN_BLK + t * 4;
    unsigned v[4]; unsigned s = 0;
    #pragma unroll
    for (int j = 0; j < 4; ++j) {
        v[j] = (base + j < M_SEG) ? cnt[base + j] : 0u;
        s += v[j];
    }
    sdata[t] = s;
    __syncthreads();
    #pragma unroll
    for (int off = 1; off < 256; off <<= 1) {
        unsigned x = (t >= off) ? sdata[t - off] : 0u;
        __syncthreads();
        if (t >= off) sdata[t] += x;
        __syncthreads();
    }
    unsigned excl = (t > 0) ? sdata[t - 1] : 0u;
    if (t == 255) bsums[blockIdx.x] = sdata[255];
    unsigned run = excl;
    #pragma unroll
    for (int j = 0; j < 4; ++j) {
        if (base + j < M_SEG) rs[base + j] = run;
        run += v[j];
    }
}

__global__ __launch_bounds__(256) void scan2_kernel(unsigned* __restrict__ bsums)
{
    __shared__ unsigned sdata[256];
    int t = threadIdx.x;
    sdata[t] = (t < SCAN_NB) ? bsums[t] : 0u;
    __syncthreads();
    #pragma unroll
    for (int off = 1; off < 256; off <<= 1) {
        unsigned x = (t >= off) ? sdata[t - off] : 0u;
        __syncthreads();
        if (t >= off) sdata[t] += x;
        __syncthreads();
    }
    if (t < SCAN_NB) bsums[t] = (t > 0) ? sdata[t - 1] : 0u;
}

__global__ __launch_bounds__(256) void scan3_kernel(
    unsigned* __restrict__ rs, const unsigned* __restrict__ bsums,
    unsigned* __restrict__ cursor)
{
    int i = blockIdx.x * blockDim.x + threadIdx.x;
    if (i < M_SEG) {
        unsigned v = rs[i] + bsums[i >> 10];
        rs[i] = v;
        cursor[i] = v;
    }
    if (i == 0) rs[M_SEG] = N_EDGES;
}

__global__ __launch_bounds__(256) void fill_kernel(
    const int* __restrict__ ei, const int* __restrict__ et,
    unsigned* __restrict__ cursor, unsigned* __restrict__ csr)
{
    int e = blockIdx.x * blockDim.x + threadIdx.x;
    if (e >= N_EDGES) return;
    int src = ei[e];
    int dst = ei[N_EDGES + e];
    int r = et[e];
    unsigned pos = atomicAdd(cursor + (size_t)r * N_NODES + dst, 1u);
    csr[pos] = (unsigned)src;
}

// ---------------------------------------------------------------------------
// Gather-aggregate v5 (fp16): 32 lanes per segment = 2 edge-slots x 16
// ch-groups (uint4 = 8 fp16 channels).  Packed v_pk_add_f16 accumulation:
// ~4x less VALU per edge than the bf16 unpack path.  One shfl_xor(16)
// slot-reduction; 16 lanes write the packed mean row.
// ---------------------------------------------------------------------------
__global__ __launch_bounds__(256) void gather_kernel(
    const unsigned short* __restrict__ Xb,   // [PAD_N][128] fp16
    const unsigned* __restrict__ rs,
    const unsigned* __restrict__ csr,
    unsigned short* __restrict__ agg)        // [2][PAD_N][128] fp16 means
{
    int t = blockIdx.x * blockDim.x + threadIdx.x;
    int seg = t >> 5;                 // 32 lanes per segment
    int lane = t & 31;
    if (seg >= M_SEG) return;
    const int e2  = lane >> 4;        // edge slot 0..1
    const int c16 = lane & 15;        // channel group (8 ch = uint4)

    unsigned start = rs[seg];
    unsigned end   = rs[seg + 1];

    const uint4* __restrict__ X4 = (const uint4*)Xb;   // 16B units

    __half2 acc[4];
    #pragma unroll
    for (int j = 0; j < 4; ++j) acc[j] = __float2half2_rn(0.f);

    for (unsigned p = start + e2; p < end; p += 2) {
        unsigned s = csr[p];
        uint4 v = X4[(s << 4) | (unsigned)c16];        // 32-bit index, SGPR base
        acc[0] = __hadd2(acc[0], *(const __half2*)&v.x);
        acc[1] = __hadd2(acc[1], *(const __half2*)&v.y);
        acc[2] = __hadd2(acc[2], *(const __half2*)&v.z);
        acc[3] = __hadd2(acc[3], *(const __half2*)&v.w);
    }

    // reduce across the 2 edge slots (lane bit 4)
    #pragma unroll
    for (int j = 0; j < 4; ++j) {
        int other = __shfl_xor(*(const int*)&acc[j], 16, 32);
        acc[j] = __hadd2(acc[j], *(const __half2*)&other);
    }

    if (e2 == 0) {
        unsigned c = end - start;
        float scale = 1.0f / (float)(c > 0u ? c : 1u);
        __half2 s2 = __float2half2_rn(scale);
        uint4 o;
        __half2 r0 = __hmul2(acc[0], s2);
        __half2 r1 = __hmul2(acc[1], s2);
        __half2 r2 = __hmul2(acc[2], s2);
        __half2 r3 = __hmul2(acc[3], s2);
        o.x = *(const unsigned*)&r0;
        o.y = *(const unsigned*)&r1;
        o.z = *(const unsigned*)&r2;
        o.w = *(const unsigned*)&r3;
        int r = seg / N_NODES;
        int n = seg % N_NODES;
        ((uint4*)(agg + ((size_t)r * PAD_N + n) * HID))[c16] = o;
    }
}

// ---------------------------------------------------------------------------
// MFMA GEMM (fp16) with double-buffered LDS B staging: 4 phases x 3 K-steps,
// two 24KB buffers.  stage(ph+1) issues before computing phase ph.
// A-frags: depth-2 register prefetch.
// ---------------------------------------------------------------------------
template <bool FINAL>
__global__ __launch_bounds__(256) void gemm_kernel(
    const unsigned short* __restrict__ Xin,   // [PAD_N][128] fp16
    const unsigned short* __restrict__ agg,   // [2][PAD_N][128] fp16
    const unsigned short* __restrict__ Wp,    // packed [12][8][64][8] fp16
    const float* __restrict__ bias,           // [128] fp32
    unsigned short* __restrict__ Hout,        // [PAD_N][128] fp16 (!FINAL)
    const float* __restrict__ Wc,             // [128][2] fp32 (FINAL)
    const float* __restrict__ bc,             // [2] fp32 (FINAL)
    float* __restrict__ Out)                  // [N][2] fp32 (FINAL)
{
    __shared__ unsigned short ldsB[2][3 * 8 * 512];   // 2 x 24 KB

    const int t    = threadIdx.x;
    const int w    = t >> 6;          // wave 0..3
    const int lane = t & 63;
    const int l15  = lane & 15;
    const int quad = lane >> 4;
    const int rowbase = blockIdx.x * 128 + w * 32;   // this wave's 32 nodes
    const int koff = quad * 8;

    // stage the 24 frags of phase ph into buffer buf (6 per wave)
    auto stage = [&](int ph, int buf) {
        #pragma unroll
        for (int fi = 0; fi < 6; ++fi) {
            int f  = fi * 4 + w;          // 0..23
            int sl = f >> 3;              // phase-local K-step 0..2
            int nt = f & 7;
            int ks = ph * 3 + sl;
            const unsigned short* g = Wp + ((size_t)(ks * 8 + nt) * 64 + lane) * 8;
            unsigned short* l = &ldsB[buf][(size_t)(sl * 8 + nt) * 512];  // wave-uniform
            __builtin_amdgcn_global_load_lds(
                (const __attribute__((address_space(1))) unsigned int*)g,
                (__attribute__((address_space(3))) unsigned int*)l, 16, 0, 0);
        }
    };

    // A-frag base pointers (constant over ks)
    const unsigned short* aS0m0 = Xin + (size_t)(rowbase + l15) * 128 + koff;
    const unsigned short* aS0m1 = aS0m0 + 16 * 128;
    const unsigned short* aS1m0 = agg + (size_t)(rowbase + l15) * 128 + koff;
    const unsigned short* aS1m1 = aS1m0 + 16 * 128;
    const unsigned short* aS2m0 = aS1m0 + (size_t)PAD_N * 128;
    const unsigned short* aS2m1 = aS2m0 + 16 * 128;

    auto aload = [&](int ks, int mt) -> half8 {
        int seg = ks >> 2;
        int kc  = (ks & 3) * 32;
        const unsigned short* p =
            (seg == 0) ? (mt ? aS0m1 : aS0m0) :
            (seg == 1) ? (mt ? aS1m1 : aS1m0) :
                         (mt ? aS2m1 : aS2m0);
        return *(const half8*)(p + kc);
    };

    float4v acc[2][8];
    #pragma unroll
    for (int nt = 0; nt < 8; ++nt) {
        float bv = bias[nt * 16 + l15];
        #pragma unroll
        for (int mt = 0; mt < 2; ++mt)
            acc[mt][nt] = float4v{bv, bv, bv, bv};
    }

    half8 a0[12], a1[12];
    stage(0, 0);
    a0[0] = aload(0, 0); a1[0] = aload(0, 1);
    a0[1] = aload(1, 0); a1[1] = aload(1, 1);
    __syncthreads();                      // phase-0 B staged (vmcnt drained)

    #pragma unroll
    for (int ph = 0; ph < 4; ++ph) {
        if (ph < 3) stage(ph + 1, (ph + 1) & 1);   // overlap staging with compute
        #pragma unroll
        for (int sl = 0; sl < 3; ++sl) {
            int ks = ph * 3 + sl;
            if (ks + 2 < 12) { a0[ks + 2] = aload(ks + 2, 0); a1[ks + 2] = aload(ks + 2, 1); }
            half8 b[8];
            #pragma unroll
            for (int nt = 0; nt < 8; ++nt)
                b[nt] = *(const half8*)(&ldsB[ph & 1][(size_t)(sl * 8 + nt) * 512] + lane * 8);
            #pragma unroll
            for (int nt = 0; nt < 8; ++nt) {
                acc[0][nt] = __builtin_amdgcn_mfma_f32_16x16x32_f16(a0[ks], b[nt], acc[0][nt], 0, 0, 0);
                acc[1][nt] = __builtin_amdgcn_mfma_f32_16x16x32_f16(a1[ks], b[nt], acc[1][nt], 0, 0, 0);
            }
        }
        __syncthreads();   // readers done with buf(ph&1); stage(ph+1) drained
    }

    if (!FINAL) {
        // D layout: row = quad*4 + r, col = l15 (within each 16x16 tile)
        #pragma unroll
        for (int mt = 0; mt < 2; ++mt) {
            #pragma unroll
            for (int r = 0; r < 4; ++r) {
                int node = rowbase + mt * 16 + quad * 4 + r;
                unsigned short* hp = Hout + (size_t)node * 128 + l15;
                #pragma unroll
                for (int nt = 0; nt < 8; ++nt)
                    hp[nt * 16] = f2h(fmaxf(acc[mt][nt][r], 0.f));
            }
        }
    } else {
        float wc0[8], wc1[8];
        #pragma unroll
        for (int nt = 0; nt < 8; ++nt) {
            wc0[nt] = Wc[(nt * 16 + l15) * 2 + 0];
            wc1[nt] = Wc[(nt * 16 + l15) * 2 + 1];
        }
        float b0 = bc[0], b1 = bc[1];
        #pragma unroll
        for (int mt = 0; mt < 2; ++mt) {
            #pragma unroll
            for (int r = 0; r < 4; ++r) {
                float l0 = 0.f, l1 = 0.f;
                #pragma unroll
                for (int nt = 0; nt < 8; ++nt) {
                    float h = fmaxf(acc[mt][nt][r], 0.f);
                    l0 += h * wc0[nt];
                    l1 += h * wc1[nt];
                }
                #pragma unroll
                for (int off = 8; off > 0; off >>= 1) {
                    l0 += __shfl_down(l0, off, 16);
                    l1 += __shfl_down(l1, off, 16);
                }
                int node = rowbase + mt * 16 + quad * 4 + r;
                if (l15 == 0 && node < N_NODES) {
                    Out[(size_t)node * 2 + 0] = l0 + b0;
                    Out[(size_t)node * 2 + 1] = l1 + b1;
                }
            }
        }
    }
}

extern "C" void kernel_launch(void* const* d_in, const int* in_sizes, int n_in,
                              void* d_out, int out_size, void* d_ws, size_t ws_size,
                              hipStream_t stream)
{
    const float* x      = (const float*)d_in[0];
    const int*   ei     = (const int*)d_in[1];
    const int*   et     = (const int*)d_in[2];
    const float* Wrel1  = (const float*)d_in[3];
    const float* Wroot1 = (const float*)d_in[4];
    const float* b1     = (const float*)d_in[5];
    const float* Wrel2  = (const float*)d_in[6];
    const float* Wroot2 = (const float*)d_in[7];
    const float* b2     = (const float*)d_in[8];
    const float* Wc     = (const float*)d_in[9];
    const float* bc     = (const float*)d_in[10];
    float* out = (float*)d_out;

    char* ws = (char*)d_ws;
    size_t off = 0;
    auto alloc = [&](size_t bytes) {
        void* p = ws + off;
        off += (bytes + 255) & ~(size_t)255;
        return p;
    };
    unsigned short* aggb  = (unsigned short*)alloc((size_t)N_REL * PAD_N * HID * 2);
    unsigned short* xb    = (unsigned short*)alloc((size_t)PAD_N * IN_DIM * 2);
    unsigned short* h1b   = (unsigned short*)alloc((size_t)PAD_N * HID * 2);
    unsigned short* Wp    = (unsigned short*)alloc((size_t)2 * 12 * 8 * 64 * 8 * 2);
    unsigned*       rs    = (unsigned*)alloc((size_t)(M_SEG + 1) * 4);
    unsigned*       cursor= (unsigned*)alloc((size_t)M_SEG * 4);
    unsigned*       bsums = (unsigned*)alloc(256 * 4);
    unsigned*       csr   = (unsigned*)alloc((size_t)N_EDGES * 4);

    const int edge_blocks   = (N_EDGES + 255) / 256;
    const int seg_blocks    = (M_SEG + 255) / 256;
    const int gather_blocks = (M_SEG * 32 + 255) / 256;   // 25000
    const int gemm_blocks   = PAD_N / 128;                // 782
    const int prep_blocks   = CVT_BLOCKS + PACK_BLOCKS + HIST_BLOCKS;

    // ---- CSR build + conversions (graph identical for both layers) ----
    hipMemsetAsync(cursor, 0, (size_t)M_SEG * 4, stream);
    prep_kernel<<<prep_blocks, 256, 0, stream>>>(
        x, xb, Wroot1, Wrel1, Wroot2, Wrel2, Wp, ei, et, cursor);
    scan1_kernel<<<SCAN_NB, 256, 0, stream>>>(cursor, rs, bsums);
    scan2_kernel<<<1, 256, 0, stream>>>(bsums);
    scan3_kernel<<<seg_blocks, 256, 0, stream>>>(rs, bsums, cursor);
    fill_kernel<<<edge_blocks, 256, 0, stream>>>(ei, et, cursor, csr);

    // ---- layer 1 ----
    gather_kernel<<<gather_blocks, 256, 0, stream>>>(xb, rs, csr, aggb);
    gemm_kernel<false><<<gemm_blocks, 256, 0, stream>>>(
        xb, aggb, Wp, b1, h1b, nullptr, nullptr, nullptr);

    // ---- layer 2 ----
    gather_kernel<<<gather_blocks, 256, 0, stream>>>(h1b, rs, csr, aggb);
    gemm_kernel<true><<<gemm_blocks, 256, 0, stream>>>(
        h1b, aggb, Wp + (size_t)12 * 8 * 64 * 8, b2, nullptr, Wc, bc, out);
}